// Round 1
// baseline (851.407 us; speedup 1.0000x reference)
//
#include <hip/hip_runtime.h>

// Sparse submanifold 3x3x3 conv (64->64) + BatchNorm(batch stats) + LeakyReLU(0.01)
// Strategy: rulebook (spconv-style). Random 1.5% density => avg ~1.4 valid taps/voxel.
//   K1 memset grid=-1, cnt/stats=0
//   K2 scatter voxel index into dense grid
//   K3 build per-offset (i,j) pair lists (26 off-center offsets; center handled separately)
//   K4 center GEMM: out = feat @ W[13]  (plain store => also initializes out)
//   K5 per-offset gather-GEMM, atomicAdd scatter into out
//   K6 channel sum/sumsq reduction
//   K7 normalize + leaky relu (in place on out)

#define DD 96
#define HH 320
#define WW 320
#define GRID_ELEMS (DD * HH * WW)
#define CIN 64
#define COUT 64
#define PAIR_CAP 32768   // per-offset list capacity; E[count]~2300, sigma~48 => safe
#define EPSV 1e-5f
#define SLOPE 0.01f

__global__ void scatter_k(const int* __restrict__ coords, int* __restrict__ grid, int N) {
    int i = blockIdx.x * 256 + threadIdx.x;
    if (i >= N) return;
    int z = coords[3 * i], y = coords[3 * i + 1], x = coords[3 * i + 2];
    grid[(z * HH + y) * WW + x] = i;
}

__global__ void rulebook_k(const int* __restrict__ coords, const int* __restrict__ grid,
                           int* __restrict__ cnt, int2* __restrict__ pairs, int N) {
    int i = blockIdx.x * 256 + threadIdx.x;
    if (i >= N) return;
    int z = coords[3 * i], y = coords[3 * i + 1], x = coords[3 * i + 2];
    int k = 0;
    for (int dz = -1; dz <= 1; ++dz)
        for (int dy = -1; dy <= 1; ++dy)
            for (int dx = -1; dx <= 1; ++dx, ++k) {
                if (k == 13) continue;  // center: identity, handled by center_k
                int nz = z + dz, ny = y + dy, nx = x + dx;
                if (nz < 0 || nz >= DD || ny < 0 || ny >= HH || nx < 0 || nx >= WW) continue;
                int j = grid[(nz * HH + ny) * WW + nx];
                if (j >= 0) {
                    int pos = atomicAdd(&cnt[k], 1);
                    if (pos < PAIR_CAP) pairs[k * PAIR_CAP + pos] = make_int2(i, j);
                }
            }
}

__device__ __forceinline__ void accum_row(const float* __restrict__ fr,
                                          const float* __restrict__ wl,
                                          float4 acc[16]) {
#pragma unroll 4
    for (int ci = 0; ci < CIN; ci += 4) {
        float4 f = *(const float4*)(fr + ci);
#pragma unroll
        for (int u = 0; u < 4; ++u) {
            float fv = (&f.x)[u];
            const float4* wr = (const float4*)(wl + (ci + u) * COUT);
#pragma unroll
            for (int c = 0; c < 16; ++c) {
                float4 wv = wr[c];
                acc[c].x += fv * wv.x;
                acc[c].y += fv * wv.y;
                acc[c].z += fv * wv.z;
                acc[c].w += fv * wv.w;
            }
        }
    }
}

__global__ void center_k(const float* __restrict__ feat, const float* __restrict__ w13,
                         float* __restrict__ out, int N) {
    __shared__ float wl[CIN * COUT];
    {
        const float4* ws4 = (const float4*)w13;
        float4* wl4 = (float4*)wl;
        for (int t = threadIdx.x; t < CIN * COUT / 4; t += 256) wl4[t] = ws4[t];
    }
    __syncthreads();
    int i = blockIdx.x * 256 + threadIdx.x;
    if (i >= N) return;
    const float* fr = feat + (size_t)i * CIN;
    float4 acc[16];
#pragma unroll
    for (int c = 0; c < 16; ++c) acc[c] = make_float4(0.f, 0.f, 0.f, 0.f);
    accum_row(fr, wl, acc);
    float4* orow = (float4*)(out + (size_t)i * COUT);
#pragma unroll
    for (int c = 0; c < 16; ++c) orow[c] = acc[c];
}

__global__ void offset_k(const float* __restrict__ feat, const float* __restrict__ weight,
                         const int2* __restrict__ pairs, const int* __restrict__ cnt,
                         float* __restrict__ out) {
    int k = blockIdx.y;
    if (k >= 13) ++k;  // skip center
    int ck = cnt[k];
    if (ck > PAIR_CAP) ck = PAIR_CAP;
    if ((int)blockIdx.x * 256 >= ck) return;  // whole-block early out (uniform, before any sync)
    __shared__ float wl[CIN * COUT];
    {
        const float4* ws4 = (const float4*)(weight + (size_t)k * CIN * COUT);
        float4* wl4 = (float4*)wl;
        for (int t = threadIdx.x; t < CIN * COUT / 4; t += 256) wl4[t] = ws4[t];
    }
    __syncthreads();
    int p = (int)blockIdx.x * 256 + threadIdx.x;
    if (p >= ck) return;
    int2 pr = pairs[k * PAIR_CAP + p];
    const float* fr = feat + (size_t)pr.y * CIN;
    float4 acc[16];
#pragma unroll
    for (int c = 0; c < 16; ++c) acc[c] = make_float4(0.f, 0.f, 0.f, 0.f);
    accum_row(fr, wl, acc);
    float* orow = out + (size_t)pr.x * COUT;
#pragma unroll
    for (int c = 0; c < 16; ++c) {
        atomicAdd(&orow[4 * c + 0], acc[c].x);
        atomicAdd(&orow[4 * c + 1], acc[c].y);
        atomicAdd(&orow[4 * c + 2], acc[c].z);
        atomicAdd(&orow[4 * c + 3], acc[c].w);
    }
}

__global__ void stats_k(const float* __restrict__ out, float* __restrict__ stats, int N) {
    __shared__ float ssum[4][64];
    __shared__ float ssq[4][64];
    int c = threadIdx.x & 63, g = threadIdx.x >> 6;
    float s = 0.f, q = 0.f;
    for (int r = blockIdx.x * 4 + g; r < N; r += gridDim.x * 4) {
        float v = out[(size_t)r * 64 + c];
        s += v;
        q += v * v;
    }
    ssum[g][c] = s;
    ssq[g][c] = q;
    __syncthreads();
    if (threadIdx.x < 64) {
        float ts = ssum[0][c] + ssum[1][c] + ssum[2][c] + ssum[3][c];
        float tq = ssq[0][c] + ssq[1][c] + ssq[2][c] + ssq[3][c];
        atomicAdd(&stats[c], ts);
        atomicAdd(&stats[64 + c], tq);
    }
}

__global__ void norm_k(float* __restrict__ out, const float* __restrict__ stats,
                       const float* __restrict__ gamma, const float* __restrict__ beta, int N) {
    int idx = (int)blockIdx.x * 256 + threadIdx.x;
    int total = N * (COUT / 4);
    if (idx >= total) return;
    int c0 = (idx & 15) * 4;
    float inv = 1.0f / (float)N;
    float4 v = ((const float4*)out)[idx];
    float4 r;
#pragma unroll
    for (int u = 0; u < 4; ++u) {
        int c = c0 + u;
        float mean = stats[c] * inv;
        float var = stats[64 + c] * inv - mean * mean;
        if (var < 0.f) var = 0.f;
        float sc = gamma[c] * rsqrtf(var + EPSV);
        float sh = beta[c] - mean * sc;
        float y = (&v.x)[u] * sc + sh;
        (&r.x)[u] = (y >= 0.f) ? y : SLOPE * y;
    }
    ((float4*)out)[idx] = r;
}

extern "C" void kernel_launch(void* const* d_in, const int* in_sizes, int n_in,
                              void* d_out, int out_size, void* d_ws, size_t ws_size,
                              hipStream_t stream) {
    const float* feat   = (const float*)d_in[0];
    const int*   coords = (const int*)d_in[1];
    const float* weight = (const float*)d_in[2];
    const float* gamma  = (const float*)d_in[3];
    const float* beta   = (const float*)d_in[4];
    float* out = (float*)d_out;
    int N = in_sizes[0] / CIN;

    // workspace layout (total ~44.3 MB)
    char* ws = (char*)d_ws;
    int* grid = (int*)ws;                                   // GRID_ELEMS * 4 = 39,321,600 B
    size_t off = (size_t)GRID_ELEMS * 4;
    int* cnt = (int*)(ws + off);                            // 128 B (27 counters, padded)
    float* stats = (float*)(ws + off + 128);                // 512 B (sum[64], sumsq[64])
    int2* pairs = (int2*)(ws + off + 1024);                 // 27 * PAIR_CAP * 8 B = 7 MB

    hipMemsetAsync(grid, 0xFF, (size_t)GRID_ELEMS * 4, stream);  // all -1
    hipMemsetAsync(ws + off, 0, 1024, stream);                   // counters + stats

    int nb = (N + 255) / 256;
    scatter_k<<<nb, 256, 0, stream>>>(coords, grid, N);
    rulebook_k<<<nb, 256, 0, stream>>>(coords, grid, cnt, pairs, N);
    center_k<<<nb, 256, 0, stream>>>(feat, weight + 13 * CIN * COUT, out, N);
    offset_k<<<dim3(PAIR_CAP / 256, 26), 256, 0, stream>>>(feat, weight, pairs, cnt, out);
    stats_k<<<1024, 256, 0, stream>>>(out, stats, N);
    int nb4 = (N * (COUT / 4) + 255) / 256;
    norm_k<<<nb4, 256, 0, stream>>>(out, stats, gamma, beta, N);
}